// Round 20
// baseline (24.856 us; speedup 1.0000x reference)
//
#include <hip/hip_runtime.h>
#include <math.h>

#define SEQ 4096
#define NBATCH 4
#define SGRP 64      // s-rows per attn block (two 32-col MFMA tiles sharing K/V)
#define TWAVES 8     // waves per attn block
#define TBLK 4       // t-split: blocks per s-group (queue depth + backfill)
#define TCH (SEQ / TBLK / TWAVES)  // 128 t per wave
#define TT 32        // t per tile (one 32x32x16 QK MFMA per s-half)
#define VTILE 288    // shorts per V tile: 9 c-rows x 32 t
#define NGRP (NBATCH * SEQ / SGRP)  // 256 s-groups

typedef _Float16 f16;
typedef __attribute__((ext_vector_type(8))) _Float16 f16x8;
typedef __attribute__((ext_vector_type(8))) __bf16 bf16x8;
typedef __attribute__((ext_vector_type(16))) float f32x16;
typedef __attribute__((ext_vector_type(4))) unsigned u32x4;
typedef __attribute__((ext_vector_type(2))) unsigned u32x2;

__device__ __forceinline__ float fexp2(float x) {
#if __has_builtin(__builtin_amdgcn_exp2f)
  return __builtin_amdgcn_exp2f(x);
#else
  return exp2f(x);
#endif
}

// lane l<32 of x keeps x; x.hi-lanes <-> y.lo-lanes exchanged.
__device__ __forceinline__ u32x2 pswap(unsigned a, unsigned b) {
#if __has_builtin(__builtin_amdgcn_permlane32_swap)
  return __builtin_amdgcn_permlane32_swap(a, b, false, false);
#else
  asm volatile("v_permlane32_swap_b32 %0, %1" : "+v"(a), "+v"(b));
  u32x2 r; r[0] = a; r[1] = b; return r;
#endif
}

// exp2 pair -> packed bf16x2 dword, TRUNCATED mantissa. Truncation bias
// cancels to first order in the softmax ratio (R10/R11: absmax == RNE).
__device__ __forceinline__ unsigned exp2_pk_bf16(float a, float b) {
  unsigned e0 = __builtin_bit_cast(unsigned, fexp2(a));
  unsigned e1 = __builtin_bit_cast(unsigned, fexp2(b));
  return __builtin_amdgcn_perm(e1, e0, 0x07060302u);  // [e1.hi16 : e0.hi16]
}

// float -> bf16 bits, RNE bit-twiddle (packing kernel; not hot).
__device__ __forceinline__ unsigned short f2bf(float f) {
  unsigned u = __builtin_bit_cast(unsigned, f);
  u += 0x7FFF + ((u >> 16) & 1);
  return (unsigned short)(u >> 16);
}

// Clifford Cl(3,0): sign of e_a * e_b (bitmask args).
__device__ __forceinline__ float cl_sign(int amask, int bmask) {
  int cnt = 0, aa = amask >> 1;
  while (aa) { cnt += __popc(aa & bmask); aa >>= 1; }
  return (cnt & 1) ? -1.f : 1.f;
}

// ---------------------------------------------------------------------------
// Kernel 1: fused {param-matrix build} + {Q/K/V projection & packing}.
//  Qp[row][16] f16 = [qhi(8) | qlo(8)]   (B-operand; lane half selects)
//  Kp[row][8]  f16 = khi                  (A-operand)
//  Vt[b][s/32][c][s%32] bf16 bits (c=0..8): tile-local layout (R14).
// ---------------------------------------------------------------------------
__global__ __launch_bounds__(128) void ck_qkv(const float* __restrict__ x,
                                              const float* __restrict__ wq,
                                              const float* __restrict__ bq,
                                              const float* __restrict__ wk,
                                              const float* __restrict__ bk,
                                              const float* __restrict__ wv,
                                              const float* __restrict__ bv,
                                              f16* __restrict__ Qp,
                                              f16* __restrict__ Kp,
                                              unsigned short* __restrict__ Vt) {
  __shared__ float Pl[288];
  const int blades[8] = {0, 1, 2, 4, 3, 5, 6, 7};
  int tid = threadIdx.x;

  if (tid < 64) {
    int j = tid >> 3, k = tid & 7;
    int bj = blades[j];
    float mq = 0.f, mk = 0.f, mv = 0.f;
    for (int i = 0; i < 8; ++i) {
      int ai = blades[i];
      if (blades[ai ^ bj] != k) continue;
      float sgn = cl_sign(ai, bj);
      mq += sgn * wq[i]; mk += sgn * wk[i]; mv += sgn * wv[i];
    }
    float c0 = cl_sign(blades[k], blades[k]);  // diagonal of scalar-part table
    const float F = 0.72134752044448170368f;   // 0.5 * log2(e)
    Pl[tid]       = mq * c0 * F;
    Pl[64 + tid]  = mk;
    Pl[128 + tid] = mv;
    if (j == 0) {
      Pl[256 + k] = bq[k] * c0 * F;
      Pl[264 + k] = bk[k];
      Pl[272 + k] = bv[k];
    }
  }
  __syncthreads();

  int row = blockIdx.x * 128 + tid;  // grid sized exactly to B*S
  int b = row >> 12;
  int s = row & (SEQ - 1);
  const float4* x4 = (const float4*)(x + (size_t)row * 8);
  float4 xa = x4[0], xb = x4[1];
  float xr[8] = {xa.x, xa.y, xa.z, xa.w, xb.x, xb.y, xb.z, xb.w};
  float q[8], k[8], v[8];
#pragma unroll
  for (int c = 0; c < 8; ++c) { q[c] = Pl[256 + c]; k[c] = Pl[264 + c]; v[c] = Pl[272 + c]; }
#pragma unroll
  for (int j = 0; j < 8; ++j) {
    float xj = xr[j];
#pragma unroll
    for (int c = 0; c < 8; ++c) {
      q[c] = fmaf(xj, Pl[j * 8 + c], q[c]);
      k[c] = fmaf(xj, Pl[64 + j * 8 + c], k[c]);
      v[c] = fmaf(xj, Pl[128 + j * 8 + c], v[c]);
    }
  }
  f16x8 qa, qb, ka;
#pragma unroll
  for (int c = 0; c < 8; ++c) {
    f16 h = (f16)q[c];
    qa[c] = h;
    qb[c] = (f16)(q[c] - (float)h);
    ka[c] = (f16)k[c];
  }
  f16x8* qrow = (f16x8*)(Qp + (size_t)row * 16);
  qrow[0] = qa; qrow[1] = qb;
  *(f16x8*)(Kp + (size_t)row * 8) = ka;
  // tile-local V write: tile = s>>5, off = s&31
  unsigned short* vt = Vt + ((size_t)b * (SEQ / 32) + (s >> 5)) * VTILE + (s & 31);
#pragma unroll
  for (int c = 0; c < 8; ++c) vt[c * 32] = f2bf(v[c]);
  vt[8 * 32] = 0x3F80;  // 1.0 bf16 (denominator ones-row)
}

// ---------------------------------------------------------------------------
// Kernel 2: 32x32x16-MFMA flash attention main loop (R17 structure: two
// 32-s chains sharing each K/V load). R20: t-SPLIT GRID — each s-group's
// t-range is split across TBLK=4 blocks (8 waves x 128 t each); grid = 1024
// blocks of 512 thr -> 2 resident + 2 queued per CU. Rationale: R15's REP=4
// ran 1.6x better per-unit (block-queue backfill over barrier/tail drain +
// L1 warmth from same-K/V reads). tb-major block order: co-scheduled blocks
// read the SAME t-quarter -> L1/L2 warmth. Blocks write [64][9] f32 partials
// to d_ws; ck_comb reduces TBLK partials + Mo transform.
// ---------------------------------------------------------------------------
__global__ __launch_bounds__(512, 4) void ck_attn(const f16* __restrict__ Qp,
                                                  const f16* __restrict__ Kp,
                                                  const unsigned short* __restrict__ Vt,
                                                  float* __restrict__ Pt) {
  __shared__ float Lo[TWAVES][SGRP][9];

  const int tid = threadIdx.x;
  const int w = tid >> 6;
  const int lane = tid & 63;
  const int ls = lane & 31;   // s-column (QK/PV), t-row (A-frag), c-row (V)
  const int hf = lane >> 5;   // k-half selector
  const int bg = blockIdx.x & (NGRP - 1);  // s-group (tb-major order)
  const int tb = blockIdx.x >> 8;          // t-quarter
  const int rowbase = bg * SGRP;
  const int b = rowbase >> 12;
  const int tbase = tb * (SEQ / TBLK);     // this block's t-range start

  // Q B-frags for the two 32-row s-halves (hoisted)
  f16x8 qf0 = *(const f16x8*)(Qp + (size_t)(rowbase + ls) * 16 + 8 * hf);
  f16x8 qf1 = *(const f16x8*)(Qp + (size_t)(rowbase + 32 + ls) * 16 + 8 * hf);

  f32x16 acc0 = {0.f, 0.f, 0.f, 0.f, 0.f, 0.f, 0.f, 0.f,
                 0.f, 0.f, 0.f, 0.f, 0.f, 0.f, 0.f, 0.f};
  f32x16 acc1 = acc0;
  const f32x16 zero = acc0;

  const f16* kbase = Kp + ((size_t)b * SEQ + tbase + w * TCH + ls) * 8;
  // tile-local V: first tile index = tbase/32 + w*(TCH/32)
  const unsigned short* vbase =
      Vt + ((size_t)b * (SEQ / 32) + (tbase >> 5) + w * (TCH / 32)) * VTILE +
      (ls <= 8 ? ls : 8) * 32 + 8 * hf;

  const int NIT = TCH / TT;  // 4 tiles per wave

#pragma unroll 1
  for (int it = 0; it < NIT; ++it) {
    const int t0 = it * TT;
    // ONE load triple serves both s-half chains
    f16x8 kf = *(const f16x8*)(kbase + (size_t)t0 * 8);
    u32x4 v0 = *(const u32x4*)(vbase + (size_t)it * VTILE);
    u32x4 v1 = *(const u32x4*)(vbase + (size_t)it * VTILE + 16);

    // both QK MFMAs back-to-back (independent chains, shared A-operand)
    f32x16 s0 = __builtin_amdgcn_mfma_f32_32x32x16_f16(kf, qf0, zero, 0, 0, 0);
    f32x16 s1 = __builtin_amdgcn_mfma_f32_32x32x16_f16(kf, qf1, zero, 0, 0, 0);

    // ---- chain 0 softmax + PV ----
    {
      unsigned d0 = exp2_pk_bf16(s0[0], s0[1]);
      unsigned d1 = exp2_pk_bf16(s0[2], s0[3]);
      unsigned d2 = exp2_pk_bf16(s0[4], s0[5]);
      unsigned d3 = exp2_pk_bf16(s0[6], s0[7]);
      u32x2 r02 = pswap(d0, d2);
      u32x2 r13 = pswap(d1, d3);
      u32x4 pb0 = {r02[0], r13[0], r02[1], r13[1]};
      acc0 = __builtin_amdgcn_mfma_f32_32x32x16_bf16(
          __builtin_bit_cast(bf16x8, v0), __builtin_bit_cast(bf16x8, pb0), acc0, 0, 0, 0);
      unsigned d4 = exp2_pk_bf16(s0[8], s0[9]);
      unsigned d5 = exp2_pk_bf16(s0[10], s0[11]);
      unsigned d6 = exp2_pk_bf16(s0[12], s0[13]);
      unsigned d7 = exp2_pk_bf16(s0[14], s0[15]);
      u32x2 r46 = pswap(d4, d6);
      u32x2 r57 = pswap(d5, d7);
      u32x4 pb1 = {r46[0], r57[0], r46[1], r57[1]};
      acc0 = __builtin_amdgcn_mfma_f32_32x32x16_bf16(
          __builtin_bit_cast(bf16x8, v1), __builtin_bit_cast(bf16x8, pb1), acc0, 0, 0, 0);
    }
    // ---- chain 1 softmax + PV ----
    {
      unsigned d0 = exp2_pk_bf16(s1[0], s1[1]);
      unsigned d1 = exp2_pk_bf16(s1[2], s1[3]);
      unsigned d2 = exp2_pk_bf16(s1[4], s1[5]);
      unsigned d3 = exp2_pk_bf16(s1[6], s1[7]);
      u32x2 r02 = pswap(d0, d2);
      u32x2 r13 = pswap(d1, d3);
      u32x4 pb0 = {r02[0], r13[0], r02[1], r13[1]};
      acc1 = __builtin_amdgcn_mfma_f32_32x32x16_bf16(
          __builtin_bit_cast(bf16x8, v0), __builtin_bit_cast(bf16x8, pb0), acc1, 0, 0, 0);
      unsigned d4 = exp2_pk_bf16(s1[8], s1[9]);
      unsigned d5 = exp2_pk_bf16(s1[10], s1[11]);
      unsigned d6 = exp2_pk_bf16(s1[12], s1[13]);
      unsigned d7 = exp2_pk_bf16(s1[14], s1[15]);
      u32x2 r46 = pswap(d4, d6);
      u32x2 r57 = pswap(d5, d7);
      u32x4 pb1 = {r46[0], r57[0], r46[1], r57[1]};
      acc1 = __builtin_amdgcn_mfma_f32_32x32x16_bf16(
          __builtin_bit_cast(bf16x8, v1), __builtin_bit_cast(bf16x8, pb1), acc1, 0, 0, 0);
    }
  }

  // wave partials: chain0 -> rows ls, chain1 -> rows 32+ls.
  // lanes<32 carry blades 0-3 + denom (r4); lanes>=32 carry blades 4-7.
  if (hf == 0) {
    Lo[w][ls][0] = acc0[0]; Lo[w][ls][1] = acc0[1];
    Lo[w][ls][2] = acc0[2]; Lo[w][ls][3] = acc0[3];
    Lo[w][ls][8] = acc0[4];
    Lo[w][32 + ls][0] = acc1[0]; Lo[w][32 + ls][1] = acc1[1];
    Lo[w][32 + ls][2] = acc1[2]; Lo[w][32 + ls][3] = acc1[3];
    Lo[w][32 + ls][8] = acc1[4];
  } else {
    Lo[w][ls][4] = acc0[0]; Lo[w][ls][5] = acc0[1];
    Lo[w][ls][6] = acc0[2]; Lo[w][ls][7] = acc0[3];
    Lo[w][32 + ls][4] = acc1[0]; Lo[w][32 + ls][5] = acc1[1];
    Lo[w][32 + ls][6] = acc1[2]; Lo[w][32 + ls][7] = acc1[3];
  }
  __syncthreads();

  // sum 8 wave-partials per (s, j), write block partial to global.
  // 576 cells over 512 threads: <=2 iterations.
  float* pt = Pt + ((size_t)(bg * TBLK + tb) * SGRP) * 9;
  for (int idx = tid; idx < SGRP * 9; idx += 512) {
    int s = idx / 9, j = idx - s * 9;
    float sum = 0.f;
#pragma unroll
    for (int w2 = 0; w2 < TWAVES; ++w2) sum += Lo[w2][s][j];
    pt[idx] = sum;
  }
}

// ---------------------------------------------------------------------------
// Kernel 3: combine TBLK partials per s-row, normalize, fused Mo transform.
// One thread per (row, ko): 16384*8 threads = 512 blocks x 256.
// ---------------------------------------------------------------------------
__global__ __launch_bounds__(256) void ck_comb(const float* __restrict__ Pt,
                                               const float* __restrict__ wo,
                                               const float* __restrict__ bo,
                                               float* __restrict__ out) {
  __shared__ float MoL[72];  // [0..63] Mo[j][k], [64..71] bo
  const int tid = threadIdx.x;
  if (tid < 64) {
    const int blades[8] = {0, 1, 2, 4, 3, 5, 6, 7};
    int j = tid >> 3, k = tid & 7;
    int bj = blades[j];
    float mo = 0.f;
    for (int i = 0; i < 8; ++i) {
      int ai = blades[i];
      if (blades[ai ^ bj] != k) continue;
      mo += cl_sign(ai, bj) * wo[i];
    }
    MoL[tid] = mo;
    if (j == 0) MoL[64 + k] = bo[k];
  }
  __syncthreads();

  int g = blockIdx.x * 256 + tid;
  int row = g >> 3, ko = g & 7;
  int bg = row >> 6, s = row & (SGRP - 1);

  const float* base = Pt + ((size_t)(bg * TBLK) * SGRP + s) * 9;
  float sum[9];
#pragma unroll
  for (int j = 0; j < 9; ++j) sum[j] = 0.f;
#pragma unroll
  for (int tb = 0; tb < TBLK; ++tb) {
    const float* p = base + (size_t)tb * SGRP * 9;
#pragma unroll
    for (int j = 0; j < 9; ++j) sum[j] += p[j];
  }
  float inv = 1.f / sum[8];
  float a = MoL[64 + ko];
#pragma unroll
  for (int j = 0; j < 8; ++j) a = fmaf(sum[j] * inv, MoL[j * 8 + ko], a);
  out[(size_t)row * 8 + ko] = a;
}

// ---------------------------------------------------------------------------
extern "C" void kernel_launch(void* const* d_in, const int* in_sizes, int n_in,
                              void* d_out, int out_size, void* d_ws, size_t ws_size,
                              hipStream_t stream) {
  const float* x  = (const float*)d_in[0];
  const float* wq = (const float*)d_in[1];
  const float* bq = (const float*)d_in[2];
  const float* wk = (const float*)d_in[3];
  const float* bk = (const float*)d_in[4];
  const float* wv = (const float*)d_in[5];
  const float* bv = (const float*)d_in[6];
  const float* wo = (const float*)d_in[7];
  const float* bo = (const float*)d_in[8];

  f16* Qp = (f16*)d_ws;                                 // [B*S][16] f16 = 512 KB
  f16* Kp = Qp + (size_t)NBATCH * SEQ * 16;             // [B*S][8]  f16 = 256 KB
  unsigned short* Vt = (unsigned short*)(Kp + (size_t)NBATCH * SEQ * 8);  // [B][S/32][9][32] = 288 KB
  float* Pt = (float*)(Vt + (size_t)NBATCH * (SEQ / 32) * VTILE);  // [256*4][64][9] f32 = 2.36 MB
  float* outp = (float*)d_out;

  hipLaunchKernelGGL(ck_qkv, dim3(NBATCH * SEQ / 128), dim3(128), 0, stream,
                     x, wq, bq, wk, bk, wv, bv, Qp, Kp, Vt);
  hipLaunchKernelGGL(ck_attn, dim3(NGRP * TBLK), dim3(512), 0, stream,
                     Qp, Kp, Vt, Pt);
  hipLaunchKernelGGL(ck_comb, dim3(NBATCH * SEQ * 8 / 256), dim3(256), 0, stream,
                     Pt, wo, bo, outp);
}

// Round 21
// 21.331 us; speedup vs baseline: 1.1653x; 1.1653x over previous
//
#include <hip/hip_runtime.h>
#include <math.h>

#define SEQ 4096
#define NBATCH 4
#define SGRP 64      // s-rows per attn block (two 32-col MFMA tiles sharing K/V)
#define TWAVES 16    // waves per block (t-split)
#define TCHUNK (SEQ / TWAVES)  // 256 t per wave
#define TT 32        // t per tile (one 32x32x16 QK MFMA per s-half)
#define VTILE 288    // shorts per V tile: 9 c-rows x 32 t

typedef _Float16 f16;
typedef __attribute__((ext_vector_type(8))) _Float16 f16x8;
typedef __attribute__((ext_vector_type(8))) __bf16 bf16x8;
typedef __attribute__((ext_vector_type(16))) float f32x16;
typedef __attribute__((ext_vector_type(4))) unsigned u32x4;
typedef __attribute__((ext_vector_type(2))) unsigned u32x2;

__device__ __forceinline__ float fexp2(float x) {
#if __has_builtin(__builtin_amdgcn_exp2f)
  return __builtin_amdgcn_exp2f(x);
#else
  return exp2f(x);
#endif
}

// lane l<32 of x keeps x; x.hi-lanes <-> y.lo-lanes exchanged.
__device__ __forceinline__ u32x2 pswap(unsigned a, unsigned b) {
#if __has_builtin(__builtin_amdgcn_permlane32_swap)
  return __builtin_amdgcn_permlane32_swap(a, b, false, false);
#else
  asm volatile("v_permlane32_swap_b32 %0, %1" : "+v"(a), "+v"(b));
  u32x2 r; r[0] = a; r[1] = b; return r;
#endif
}

// exp2 pair -> packed bf16x2 dword, TRUNCATED mantissa. Truncation bias
// cancels to first order in the softmax ratio (R10/R11: absmax == RNE).
__device__ __forceinline__ unsigned exp2_pk_bf16(float a, float b) {
  unsigned e0 = __builtin_bit_cast(unsigned, fexp2(a));
  unsigned e1 = __builtin_bit_cast(unsigned, fexp2(b));
  return __builtin_amdgcn_perm(e1, e0, 0x07060302u);  // [e1.hi16 : e0.hi16]
}

// float -> bf16 bits, RNE bit-twiddle (packing kernel; not hot).
__device__ __forceinline__ unsigned short f2bf(float f) {
  unsigned u = __builtin_bit_cast(unsigned, f);
  u += 0x7FFF + ((u >> 16) & 1);
  return (unsigned short)(u >> 16);
}

// Clifford Cl(3,0): sign of e_a * e_b (bitmask args).
__device__ __forceinline__ float cl_sign(int amask, int bmask) {
  int cnt = 0, aa = amask >> 1;
  while (aa) { cnt += __popc(aa & bmask); aa >>= 1; }
  return (cnt & 1) ? -1.f : 1.f;
}

// ---------------------------------------------------------------------------
// Kernel 1: fused {param-matrix build} + {Q/K/V projection & packing}.
//  Qp[row][16] f16 = [qhi(8) | qlo(8)]   (B-operand; lane half selects)
//  Kp[row][8]  f16 = khi                  (A-operand)
//  Vt[b][s/32][c][s%32] bf16 bits (c=0..8): tile-local layout (R14).
// ---------------------------------------------------------------------------
__global__ __launch_bounds__(128) void ck_qkv(const float* __restrict__ x,
                                              const float* __restrict__ wq,
                                              const float* __restrict__ bq,
                                              const float* __restrict__ wk,
                                              const float* __restrict__ bk,
                                              const float* __restrict__ wv,
                                              const float* __restrict__ bv,
                                              f16* __restrict__ Qp,
                                              f16* __restrict__ Kp,
                                              unsigned short* __restrict__ Vt) {
  __shared__ float Pl[288];
  const int blades[8] = {0, 1, 2, 4, 3, 5, 6, 7};
  int tid = threadIdx.x;

  if (tid < 64) {
    int j = tid >> 3, k = tid & 7;
    int bj = blades[j];
    float mq = 0.f, mk = 0.f, mv = 0.f;
    for (int i = 0; i < 8; ++i) {
      int ai = blades[i];
      if (blades[ai ^ bj] != k) continue;
      float sgn = cl_sign(ai, bj);
      mq += sgn * wq[i]; mk += sgn * wk[i]; mv += sgn * wv[i];
    }
    float c0 = cl_sign(blades[k], blades[k]);  // diagonal of scalar-part table
    const float F = 0.72134752044448170368f;   // 0.5 * log2(e)
    Pl[tid]       = mq * c0 * F;
    Pl[64 + tid]  = mk;
    Pl[128 + tid] = mv;
    if (j == 0) {
      Pl[256 + k] = bq[k] * c0 * F;
      Pl[264 + k] = bk[k];
      Pl[272 + k] = bv[k];
    }
  }
  __syncthreads();

  int row = blockIdx.x * 128 + tid;  // grid sized exactly to B*S
  int b = row >> 12;
  int s = row & (SEQ - 1);
  const float4* x4 = (const float4*)(x + (size_t)row * 8);
  float4 xa = x4[0], xb = x4[1];
  float xr[8] = {xa.x, xa.y, xa.z, xa.w, xb.x, xb.y, xb.z, xb.w};
  float q[8], k[8], v[8];
#pragma unroll
  for (int c = 0; c < 8; ++c) { q[c] = Pl[256 + c]; k[c] = Pl[264 + c]; v[c] = Pl[272 + c]; }
#pragma unroll
  for (int j = 0; j < 8; ++j) {
    float xj = xr[j];
#pragma unroll
    for (int c = 0; c < 8; ++c) {
      q[c] = fmaf(xj, Pl[j * 8 + c], q[c]);
      k[c] = fmaf(xj, Pl[64 + j * 8 + c], k[c]);
      v[c] = fmaf(xj, Pl[128 + j * 8 + c], v[c]);
    }
  }
  f16x8 qa, qb, ka;
#pragma unroll
  for (int c = 0; c < 8; ++c) {
    f16 h = (f16)q[c];
    qa[c] = h;
    qb[c] = (f16)(q[c] - (float)h);
    ka[c] = (f16)k[c];
  }
  f16x8* qrow = (f16x8*)(Qp + (size_t)row * 16);
  qrow[0] = qa; qrow[1] = qb;
  *(f16x8*)(Kp + (size_t)row * 8) = ka;
  // tile-local V write: tile = s>>5, off = s&31
  unsigned short* vt = Vt + ((size_t)b * (SEQ / 32) + (s >> 5)) * VTILE + (s & 31);
#pragma unroll
  for (int c = 0; c < 8; ++c) vt[c * 32] = f2bf(v[c]);
  vt[8 * 32] = 0x3F80;  // 1.0 bf16 (denominator ones-row)
}

// ---------------------------------------------------------------------------
// Kernel 2: 32x32x16-MFMA flash attention, no-max softmax (bf16 P: finite for
// any logit). R21 = R17 RESTORED (measured best, 21.19us). One block = 64
// s-rows (two 32-s chains SHARING each K/V load triple), 16 waves t-split
// (256 t each). Session ledger: dual-chain ILP +1.6us, tile-local V +0.2,
// K/V-sharing +0.3; all occupancy/prefetch/unroll/setprio/shared-acc/
// VGPR-pin/t-split experiments null or negative. Remaining 2-3x over the
// ~5us pipe floor is dependency-stall structure beyond HIP-source reach
// (m97 precedent: needs inline-asm K-loop / wave specialization).
// Per tile:
//   s0 = mfma_32x32x16_f16(kf, qf0, 0), s1 = mfma(kf, qf1, 0)  [shared kf]
//     -> lane l holds S[t=(r&3)+8(r>>2)+4(l>>5)][s=l&31], r=0..15
//   chain i: 16x exp2 -> 8 packed bf16 dwords -> 2 pswap per 16-t half ->
//   2 PV MFMAs with shared v0/v1 into acc_i
//     -> lane holds O^T[c=(r&3)+8(r>>2)+4(l>>5)][s=l&31]; c=8 is the denom.
//   (V rows c>8 clamp to ones-row; junk D rows 9..31 never stored.)
// Combine 16 wave-partials in LDS (Lo[16][64][9]), normalize, Mo transform.
// ---------------------------------------------------------------------------
__global__ __launch_bounds__(1024, 4) void ck_attn(const f16* __restrict__ Qp,
                                                   const f16* __restrict__ Kp,
                                                   const unsigned short* __restrict__ Vt,
                                                   const float* __restrict__ wo,
                                                   const float* __restrict__ bo,
                                                   float* __restrict__ out) {
  __shared__ float Lo[TWAVES][SGRP][9];
  __shared__ float MoL[72];  // [0..63] Mo[j][k], [64..71] bo

  const int tid = threadIdx.x;
  const int w = tid >> 6;
  const int lane = tid & 63;
  const int ls = lane & 31;   // s-column (QK/PV), t-row (A-frag), c-row (V)
  const int hf = lane >> 5;   // k-half selector
  const int rowbase = blockIdx.x * SGRP;
  const int b = rowbase >> 12;

  if (tid < 64) {
    const int blades[8] = {0, 1, 2, 4, 3, 5, 6, 7};
    int j = tid >> 3, k = tid & 7;
    int bj = blades[j];
    float mo = 0.f;
    for (int i = 0; i < 8; ++i) {
      int ai = blades[i];
      if (blades[ai ^ bj] != k) continue;
      mo += cl_sign(ai, bj) * wo[i];
    }
    MoL[tid] = mo;
    if (j == 0) MoL[64 + k] = bo[k];
  }

  // Q B-frags for the two 32-row s-halves (hoisted)
  f16x8 qf0 = *(const f16x8*)(Qp + (size_t)(rowbase + ls) * 16 + 8 * hf);
  f16x8 qf1 = *(const f16x8*)(Qp + (size_t)(rowbase + 32 + ls) * 16 + 8 * hf);

  f32x16 acc0 = {0.f, 0.f, 0.f, 0.f, 0.f, 0.f, 0.f, 0.f,
                 0.f, 0.f, 0.f, 0.f, 0.f, 0.f, 0.f, 0.f};
  f32x16 acc1 = acc0;
  const f32x16 zero = acc0;

  const f16* kbase = Kp + ((size_t)b * SEQ + w * TCHUNK + ls) * 8;
  // tile-local V: this wave's first tile index is w*(TCHUNK/32); lane offset
  // = c-row (clamped) * 32 + 8*hf within the 288-short tile.
  const unsigned short* vbase =
      Vt + ((size_t)b * (SEQ / 32) + w * (TCHUNK / 32)) * VTILE +
      (ls <= 8 ? ls : 8) * 32 + 8 * hf;

  const int NIT = TCHUNK / TT;  // 8 tiles per wave

#pragma unroll 1
  for (int it = 0; it < NIT; ++it) {
    const int t0 = it * TT;
    // ONE load triple serves both s-half chains
    f16x8 kf = *(const f16x8*)(kbase + (size_t)t0 * 8);
    u32x4 v0 = *(const u32x4*)(vbase + (size_t)it * VTILE);
    u32x4 v1 = *(const u32x4*)(vbase + (size_t)it * VTILE + 16);

    // both QK MFMAs back-to-back (independent chains, shared A-operand)
    f32x16 s0 = __builtin_amdgcn_mfma_f32_32x32x16_f16(kf, qf0, zero, 0, 0, 0);
    f32x16 s1 = __builtin_amdgcn_mfma_f32_32x32x16_f16(kf, qf1, zero, 0, 0, 0);

    // ---- chain 0 softmax + PV ----
    {
      unsigned d0 = exp2_pk_bf16(s0[0], s0[1]);
      unsigned d1 = exp2_pk_bf16(s0[2], s0[3]);
      unsigned d2 = exp2_pk_bf16(s0[4], s0[5]);
      unsigned d3 = exp2_pk_bf16(s0[6], s0[7]);
      u32x2 r02 = pswap(d0, d2);
      u32x2 r13 = pswap(d1, d3);
      u32x4 pb0 = {r02[0], r13[0], r02[1], r13[1]};
      acc0 = __builtin_amdgcn_mfma_f32_32x32x16_bf16(
          __builtin_bit_cast(bf16x8, v0), __builtin_bit_cast(bf16x8, pb0), acc0, 0, 0, 0);
      unsigned d4 = exp2_pk_bf16(s0[8], s0[9]);
      unsigned d5 = exp2_pk_bf16(s0[10], s0[11]);
      unsigned d6 = exp2_pk_bf16(s0[12], s0[13]);
      unsigned d7 = exp2_pk_bf16(s0[14], s0[15]);
      u32x2 r46 = pswap(d4, d6);
      u32x2 r57 = pswap(d5, d7);
      u32x4 pb1 = {r46[0], r57[0], r46[1], r57[1]};
      acc0 = __builtin_amdgcn_mfma_f32_32x32x16_bf16(
          __builtin_bit_cast(bf16x8, v1), __builtin_bit_cast(bf16x8, pb1), acc0, 0, 0, 0);
    }
    // ---- chain 1 softmax + PV ----
    {
      unsigned d0 = exp2_pk_bf16(s1[0], s1[1]);
      unsigned d1 = exp2_pk_bf16(s1[2], s1[3]);
      unsigned d2 = exp2_pk_bf16(s1[4], s1[5]);
      unsigned d3 = exp2_pk_bf16(s1[6], s1[7]);
      u32x2 r02 = pswap(d0, d2);
      u32x2 r13 = pswap(d1, d3);
      u32x4 pb0 = {r02[0], r13[0], r02[1], r13[1]};
      acc1 = __builtin_amdgcn_mfma_f32_32x32x16_bf16(
          __builtin_bit_cast(bf16x8, v0), __builtin_bit_cast(bf16x8, pb0), acc1, 0, 0, 0);
      unsigned d4 = exp2_pk_bf16(s1[8], s1[9]);
      unsigned d5 = exp2_pk_bf16(s1[10], s1[11]);
      unsigned d6 = exp2_pk_bf16(s1[12], s1[13]);
      unsigned d7 = exp2_pk_bf16(s1[14], s1[15]);
      u32x2 r46 = pswap(d4, d6);
      u32x2 r57 = pswap(d5, d7);
      u32x4 pb1 = {r46[0], r57[0], r46[1], r57[1]};
      acc1 = __builtin_amdgcn_mfma_f32_32x32x16_bf16(
          __builtin_bit_cast(bf16x8, v1), __builtin_bit_cast(bf16x8, pb1), acc1, 0, 0, 0);
    }
  }

  // wave partials: chain0 -> rows ls, chain1 -> rows 32+ls.
  // lanes<32 carry blades 0-3 + denom (r4); lanes>=32 carry blades 4-7.
  if (hf == 0) {
    Lo[w][ls][0] = acc0[0]; Lo[w][ls][1] = acc0[1];
    Lo[w][ls][2] = acc0[2]; Lo[w][ls][3] = acc0[3];
    Lo[w][ls][8] = acc0[4];
    Lo[w][32 + ls][0] = acc1[0]; Lo[w][32 + ls][1] = acc1[1];
    Lo[w][32 + ls][2] = acc1[2]; Lo[w][32 + ls][3] = acc1[3];
    Lo[w][32 + ls][8] = acc1[4];
  } else {
    Lo[w][ls][4] = acc0[0]; Lo[w][ls][5] = acc0[1];
    Lo[w][ls][6] = acc0[2]; Lo[w][ls][7] = acc0[3];
    Lo[w][32 + ls][4] = acc1[0]; Lo[w][32 + ls][5] = acc1[1];
    Lo[w][32 + ls][6] = acc1[2]; Lo[w][32 + ls][7] = acc1[3];
  }
  __syncthreads();

  // stage 1: sum 16 wave-partials per (s, j); each cell has a unique owner
  if (tid < SGRP * 9) {
    int s = tid / 9, j = tid - s * 9;
    float sum = 0.f;
#pragma unroll
    for (int w2 = 0; w2 < TWAVES; ++w2) sum += Lo[w2][s][j];
    Lo[0][s][j] = sum;
  }
  __syncthreads();

  // stage 2: normalize + fused output clifford transform
  if (tid < SGRP * 8) {
    int s = tid >> 3, ko = tid & 7;
    float inv = 1.f / Lo[0][s][8];
    float a = MoL[64 + ko];
#pragma unroll
    for (int j = 0; j < 8; ++j) a = fmaf(Lo[0][s][j] * inv, MoL[j * 8 + ko], a);
    out[(size_t)(rowbase + s) * 8 + ko] = a;
  }
}

// ---------------------------------------------------------------------------
extern "C" void kernel_launch(void* const* d_in, const int* in_sizes, int n_in,
                              void* d_out, int out_size, void* d_ws, size_t ws_size,
                              hipStream_t stream) {
  const float* x  = (const float*)d_in[0];
  const float* wq = (const float*)d_in[1];
  const float* bq = (const float*)d_in[2];
  const float* wk = (const float*)d_in[3];
  const float* bk = (const float*)d_in[4];
  const float* wv = (const float*)d_in[5];
  const float* bv = (const float*)d_in[6];
  const float* wo = (const float*)d_in[7];
  const float* bo = (const float*)d_in[8];

  f16* Qp = (f16*)d_ws;                                 // [B*S][16] f16 = 512 KB
  f16* Kp = Qp + (size_t)NBATCH * SEQ * 16;             // [B*S][8]  f16 = 256 KB
  unsigned short* Vt = (unsigned short*)(Kp + (size_t)NBATCH * SEQ * 8);  // [B][S/32][9][32] bf16 = 288 KB
  float* outp = (float*)d_out;

  hipLaunchKernelGGL(ck_qkv, dim3(NBATCH * SEQ / 128), dim3(128), 0, stream,
                     x, wq, bq, wk, bk, wv, bv, Qp, Kp, Vt);
  hipLaunchKernelGGL(ck_attn, dim3(NBATCH * SEQ / SGRP), dim3(1024), 0, stream,
                     Qp, Kp, Vt, wo, bo, outp);
}

// Round 22
// 20.973 us; speedup vs baseline: 1.1851x; 1.0170x over previous
//
#include <hip/hip_runtime.h>
#include <math.h>

#define SEQ 4096
#define NBATCH 4
#define SGRP 64      // s-rows per attn block (two 32-col MFMA tiles sharing K/V)
#define TWAVES 16    // waves per block (t-split)
#define TCHUNK (SEQ / TWAVES)  // 256 t per wave
#define TT 32        // t per tile (one 32x32x16 QK MFMA per s-half)
#define VTILE 288    // shorts per V tile: 9 c-rows x 32 t

typedef _Float16 f16;
typedef __attribute__((ext_vector_type(8))) _Float16 f16x8;
typedef __attribute__((ext_vector_type(8))) __bf16 bf16x8;
typedef __attribute__((ext_vector_type(16))) float f32x16;
typedef __attribute__((ext_vector_type(4))) unsigned u32x4;
typedef __attribute__((ext_vector_type(2))) unsigned u32x2;

__device__ __forceinline__ float fexp2(float x) {
#if __has_builtin(__builtin_amdgcn_exp2f)
  return __builtin_amdgcn_exp2f(x);
#else
  return exp2f(x);
#endif
}

// lane l<32 of x keeps x; x.hi-lanes <-> y.lo-lanes exchanged.
__device__ __forceinline__ u32x2 pswap(unsigned a, unsigned b) {
#if __has_builtin(__builtin_amdgcn_permlane32_swap)
  return __builtin_amdgcn_permlane32_swap(a, b, false, false);
#else
  asm volatile("v_permlane32_swap_b32 %0, %1" : "+v"(a), "+v"(b));
  u32x2 r; r[0] = a; r[1] = b; return r;
#endif
}

// exp2 pair -> packed bf16x2 dword, TRUNCATED mantissa. Truncation bias
// cancels to first order in the softmax ratio (R10/R11: absmax == RNE).
__device__ __forceinline__ unsigned exp2_pk_bf16(float a, float b) {
  unsigned e0 = __builtin_bit_cast(unsigned, fexp2(a));
  unsigned e1 = __builtin_bit_cast(unsigned, fexp2(b));
  return __builtin_amdgcn_perm(e1, e0, 0x07060302u);  // [e1.hi16 : e0.hi16]
}

// float -> bf16 bits, RNE bit-twiddle (packing kernel; not hot).
__device__ __forceinline__ unsigned short f2bf(float f) {
  unsigned u = __builtin_bit_cast(unsigned, f);
  u += 0x7FFF + ((u >> 16) & 1);
  return (unsigned short)(u >> 16);
}

// Clifford Cl(3,0): sign of e_a * e_b (bitmask args).
__device__ __forceinline__ float cl_sign(int amask, int bmask) {
  int cnt = 0, aa = amask >> 1;
  while (aa) { cnt += __popc(aa & bmask); aa >>= 1; }
  return (cnt & 1) ? -1.f : 1.f;
}

// ---------------------------------------------------------------------------
// Kernel 1: fused {param-matrix build} + {Q/K/V projection & packing}.
// R22: FINE-GRAINED — 8 threads per row, thread (row, c) computes component
// c of q/k/v (24 FMAs). 131072 threads = 8 waves/CU (was 0.25 waves/SIMD at
// 1 thread/row: pure latency-exposed serial chains). Per-element FMA order
// unchanged -> bit-identical outputs to R21's qkv.
//  Qp[row][16] f16 = [qhi(8) | qlo(8)]   (B-operand; lane half selects)
//  Kp[row][8]  f16 = khi                  (A-operand)
//  Vt[b][s/32][c][s%32] bf16 bits (c=0..8): tile-local layout (R14).
// ---------------------------------------------------------------------------
__global__ __launch_bounds__(256) void ck_qkv(const float* __restrict__ x,
                                              const float* __restrict__ wq,
                                              const float* __restrict__ bq,
                                              const float* __restrict__ wk,
                                              const float* __restrict__ bk,
                                              const float* __restrict__ wv,
                                              const float* __restrict__ bv,
                                              f16* __restrict__ Qp,
                                              f16* __restrict__ Kp,
                                              unsigned short* __restrict__ Vt) {
  __shared__ float Pl[288];
  const int blades[8] = {0, 1, 2, 4, 3, 5, 6, 7};
  int tid = threadIdx.x;

  if (tid < 64) {
    int j = tid >> 3, k = tid & 7;
    int bj = blades[j];
    float mq = 0.f, mk = 0.f, mv = 0.f;
    for (int i = 0; i < 8; ++i) {
      int ai = blades[i];
      if (blades[ai ^ bj] != k) continue;
      float sgn = cl_sign(ai, bj);
      mq += sgn * wq[i]; mk += sgn * wk[i]; mv += sgn * wv[i];
    }
    float c0 = cl_sign(blades[k], blades[k]);  // diagonal of scalar-part table
    const float F = 0.72134752044448170368f;   // 0.5 * log2(e)
    Pl[tid]       = mq * c0 * F;
    Pl[64 + tid]  = mk;
    Pl[128 + tid] = mv;
    if (j == 0) {
      Pl[256 + k] = bq[k] * c0 * F;
      Pl[264 + k] = bk[k];
      Pl[272 + k] = bv[k];
    }
  }
  __syncthreads();

  int gid = blockIdx.x * 256 + tid;  // grid sized exactly to B*S*8
  int row = gid >> 3;
  int c = gid & 7;
  int b = row >> 12;
  int s = row & (SEQ - 1);
  const float4* x4 = (const float4*)(x + (size_t)row * 8);
  float4 xa = x4[0], xb = x4[1];
  float xr[8] = {xa.x, xa.y, xa.z, xa.w, xb.x, xb.y, xb.z, xb.w};
  float q = Pl[256 + c], k = Pl[264 + c], v = Pl[272 + c];
#pragma unroll
  for (int j = 0; j < 8; ++j) {
    q = fmaf(xr[j], Pl[j * 8 + c], q);
    k = fmaf(xr[j], Pl[64 + j * 8 + c], k);
    v = fmaf(xr[j], Pl[128 + j * 8 + c], v);
  }
  f16 qh = (f16)q;
  f16 ql = (f16)(q - (float)qh);
  Qp[(size_t)row * 16 + c] = qh;
  Qp[(size_t)row * 16 + 8 + c] = ql;
  Kp[(size_t)row * 8 + c] = (f16)k;
  // tile-local V write: tile = s>>5, off = s&31
  unsigned short* vt = Vt + ((size_t)b * (SEQ / 32) + (s >> 5)) * VTILE + (s & 31);
  vt[c * 32] = f2bf(v);
  if (c == 0) vt[8 * 32] = 0x3F80;  // 1.0 bf16 (denominator ones-row)
}

// ---------------------------------------------------------------------------
// Kernel 2: 32x32x16-MFMA flash attention, no-max softmax (bf16 P: finite for
// any logit). R17 structure (measured best). One block = 64 s-rows (two 32-s
// chains SHARING each K/V load triple), 16 waves t-split (256 t each).
// Session ledger: dual-chain ILP +1.6us, tile-local V +0.2, K/V-sharing
// +0.3; all occupancy/prefetch/unroll/setprio/shared-acc/VGPR-pin/t-split
// experiments null or negative. Remaining 2-3x over the ~5us pipe floor is
// dependency-stall structure beyond HIP-source reach (m97 precedent: needs
// inline-asm K-loop / wave specialization).
// Per tile:
//   s0 = mfma_32x32x16_f16(kf, qf0, 0), s1 = mfma(kf, qf1, 0)  [shared kf]
//     -> lane l holds S[t=(r&3)+8(r>>2)+4(l>>5)][s=l&31], r=0..15
//   chain i: 16x exp2 -> 8 packed bf16 dwords -> 2 pswap per 16-t half ->
//   2 PV MFMAs with shared v0/v1 into acc_i
//     -> lane holds O^T[c=(r&3)+8(r>>2)+4(l>>5)][s=l&31]; c=8 is the denom.
//   (V rows c>8 clamp to ones-row; junk D rows 9..31 never stored.)
// Combine 16 wave-partials in LDS (Lo[16][64][9]), normalize, Mo transform.
// ---------------------------------------------------------------------------
__global__ __launch_bounds__(1024, 4) void ck_attn(const f16* __restrict__ Qp,
                                                   const f16* __restrict__ Kp,
                                                   const unsigned short* __restrict__ Vt,
                                                   const float* __restrict__ wo,
                                                   const float* __restrict__ bo,
                                                   float* __restrict__ out) {
  __shared__ float Lo[TWAVES][SGRP][9];
  __shared__ float MoL[72];  // [0..63] Mo[j][k], [64..71] bo

  const int tid = threadIdx.x;
  const int w = tid >> 6;
  const int lane = tid & 63;
  const int ls = lane & 31;   // s-column (QK/PV), t-row (A-frag), c-row (V)
  const int hf = lane >> 5;   // k-half selector
  const int rowbase = blockIdx.x * SGRP;
  const int b = rowbase >> 12;

  if (tid < 64) {
    const int blades[8] = {0, 1, 2, 4, 3, 5, 6, 7};
    int j = tid >> 3, k = tid & 7;
    int bj = blades[j];
    float mo = 0.f;
    for (int i = 0; i < 8; ++i) {
      int ai = blades[i];
      if (blades[ai ^ bj] != k) continue;
      mo += cl_sign(ai, bj) * wo[i];
    }
    MoL[tid] = mo;
    if (j == 0) MoL[64 + k] = bo[k];
  }

  // Q B-frags for the two 32-row s-halves (hoisted)
  f16x8 qf0 = *(const f16x8*)(Qp + (size_t)(rowbase + ls) * 16 + 8 * hf);
  f16x8 qf1 = *(const f16x8*)(Qp + (size_t)(rowbase + 32 + ls) * 16 + 8 * hf);

  f32x16 acc0 = {0.f, 0.f, 0.f, 0.f, 0.f, 0.f, 0.f, 0.f,
                 0.f, 0.f, 0.f, 0.f, 0.f, 0.f, 0.f, 0.f};
  f32x16 acc1 = acc0;
  const f32x16 zero = acc0;

  const f16* kbase = Kp + ((size_t)b * SEQ + w * TCHUNK + ls) * 8;
  // tile-local V: this wave's first tile index is w*(TCHUNK/32); lane offset
  // = c-row (clamped) * 32 + 8*hf within the 288-short tile.
  const unsigned short* vbase =
      Vt + ((size_t)b * (SEQ / 32) + w * (TCHUNK / 32)) * VTILE +
      (ls <= 8 ? ls : 8) * 32 + 8 * hf;

  const int NIT = TCHUNK / TT;  // 8 tiles per wave

#pragma unroll 1
  for (int it = 0; it < NIT; ++it) {
    const int t0 = it * TT;
    // ONE load triple serves both s-half chains
    f16x8 kf = *(const f16x8*)(kbase + (size_t)t0 * 8);
    u32x4 v0 = *(const u32x4*)(vbase + (size_t)it * VTILE);
    u32x4 v1 = *(const u32x4*)(vbase + (size_t)it * VTILE + 16);

    // both QK MFMAs back-to-back (independent chains, shared A-operand)
    f32x16 s0 = __builtin_amdgcn_mfma_f32_32x32x16_f16(kf, qf0, zero, 0, 0, 0);
    f32x16 s1 = __builtin_amdgcn_mfma_f32_32x32x16_f16(kf, qf1, zero, 0, 0, 0);

    // ---- chain 0 softmax + PV ----
    {
      unsigned d0 = exp2_pk_bf16(s0[0], s0[1]);
      unsigned d1 = exp2_pk_bf16(s0[2], s0[3]);
      unsigned d2 = exp2_pk_bf16(s0[4], s0[5]);
      unsigned d3 = exp2_pk_bf16(s0[6], s0[7]);
      u32x2 r02 = pswap(d0, d2);
      u32x2 r13 = pswap(d1, d3);
      u32x4 pb0 = {r02[0], r13[0], r02[1], r13[1]};
      acc0 = __builtin_amdgcn_mfma_f32_32x32x16_bf16(
          __builtin_bit_cast(bf16x8, v0), __builtin_bit_cast(bf16x8, pb0), acc0, 0, 0, 0);
      unsigned d4 = exp2_pk_bf16(s0[8], s0[9]);
      unsigned d5 = exp2_pk_bf16(s0[10], s0[11]);
      unsigned d6 = exp2_pk_bf16(s0[12], s0[13]);
      unsigned d7 = exp2_pk_bf16(s0[14], s0[15]);
      u32x2 r46 = pswap(d4, d6);
      u32x2 r57 = pswap(d5, d7);
      u32x4 pb1 = {r46[0], r57[0], r46[1], r57[1]};
      acc0 = __builtin_amdgcn_mfma_f32_32x32x16_bf16(
          __builtin_bit_cast(bf16x8, v1), __builtin_bit_cast(bf16x8, pb1), acc0, 0, 0, 0);
    }
    // ---- chain 1 softmax + PV ----
    {
      unsigned d0 = exp2_pk_bf16(s1[0], s1[1]);
      unsigned d1 = exp2_pk_bf16(s1[2], s1[3]);
      unsigned d2 = exp2_pk_bf16(s1[4], s1[5]);
      unsigned d3 = exp2_pk_bf16(s1[6], s1[7]);
      u32x2 r02 = pswap(d0, d2);
      u32x2 r13 = pswap(d1, d3);
      u32x4 pb0 = {r02[0], r13[0], r02[1], r13[1]};
      acc1 = __builtin_amdgcn_mfma_f32_32x32x16_bf16(
          __builtin_bit_cast(bf16x8, v0), __builtin_bit_cast(bf16x8, pb0), acc1, 0, 0, 0);
      unsigned d4 = exp2_pk_bf16(s1[8], s1[9]);
      unsigned d5 = exp2_pk_bf16(s1[10], s1[11]);
      unsigned d6 = exp2_pk_bf16(s1[12], s1[13]);
      unsigned d7 = exp2_pk_bf16(s1[14], s1[15]);
      u32x2 r46 = pswap(d4, d6);
      u32x2 r57 = pswap(d5, d7);
      u32x4 pb1 = {r46[0], r57[0], r46[1], r57[1]};
      acc1 = __builtin_amdgcn_mfma_f32_32x32x16_bf16(
          __builtin_bit_cast(bf16x8, v1), __builtin_bit_cast(bf16x8, pb1), acc1, 0, 0, 0);
    }
  }

  // wave partials: chain0 -> rows ls, chain1 -> rows 32+ls.
  // lanes<32 carry blades 0-3 + denom (r4); lanes>=32 carry blades 4-7.
  if (hf == 0) {
    Lo[w][ls][0] = acc0[0]; Lo[w][ls][1] = acc0[1];
    Lo[w][ls][2] = acc0[2]; Lo[w][ls][3] = acc0[3];
    Lo[w][ls][8] = acc0[4];
    Lo[w][32 + ls][0] = acc1[0]; Lo[w][32 + ls][1] = acc1[1];
    Lo[w][32 + ls][2] = acc1[2]; Lo[w][32 + ls][3] = acc1[3];
    Lo[w][32 + ls][8] = acc1[4];
  } else {
    Lo[w][ls][4] = acc0[0]; Lo[w][ls][5] = acc0[1];
    Lo[w][ls][6] = acc0[2]; Lo[w][ls][7] = acc0[3];
    Lo[w][32 + ls][4] = acc1[0]; Lo[w][32 + ls][5] = acc1[1];
    Lo[w][32 + ls][6] = acc1[2]; Lo[w][32 + ls][7] = acc1[3];
  }
  __syncthreads();

  // stage 1: sum 16 wave-partials per (s, j); each cell has a unique owner
  if (tid < SGRP * 9) {
    int s = tid / 9, j = tid - s * 9;
    float sum = 0.f;
#pragma unroll
    for (int w2 = 0; w2 < TWAVES; ++w2) sum += Lo[w2][s][j];
    Lo[0][s][j] = sum;
  }
  __syncthreads();

  // stage 2: normalize + fused output clifford transform
  if (tid < SGRP * 8) {
    int s = tid >> 3, ko = tid & 7;
    float inv = 1.f / Lo[0][s][8];
    float a = MoL[64 + ko];
#pragma unroll
    for (int j = 0; j < 8; ++j) a = fmaf(Lo[0][s][j] * inv, MoL[j * 8 + ko], a);
    out[(size_t)(rowbase + s) * 8 + ko] = a;
  }
}

// ---------------------------------------------------------------------------
extern "C" void kernel_launch(void* const* d_in, const int* in_sizes, int n_in,
                              void* d_out, int out_size, void* d_ws, size_t ws_size,
                              hipStream_t stream) {
  const float* x  = (const float*)d_in[0];
  const float* wq = (const float*)d_in[1];
  const float* bq = (const float*)d_in[2];
  const float* wk = (const float*)d_in[3];
  const float* bk = (const float*)d_in[4];
  const float* wv = (const float*)d_in[5];
  const float* bv = (const float*)d_in[6];
  const float* wo = (const float*)d_in[7];
  const float* bo = (const float*)d_in[8];

  f16* Qp = (f16*)d_ws;                                 // [B*S][16] f16 = 512 KB
  f16* Kp = Qp + (size_t)NBATCH * SEQ * 16;             // [B*S][8]  f16 = 256 KB
  unsigned short* Vt = (unsigned short*)(Kp + (size_t)NBATCH * SEQ * 8);  // [B][S/32][9][32] bf16 = 288 KB
  float* outp = (float*)d_out;

  hipLaunchKernelGGL(ck_qkv, dim3(NBATCH * SEQ * 8 / 256), dim3(256), 0, stream,
                     x, wq, bq, wk, bk, wv, bv, Qp, Kp, Vt);
  hipLaunchKernelGGL(ck_attn, dim3(NBATCH * SEQ / SGRP), dim3(1024), 0, stream,
                     Qp, Kp, Vt, wo, bo, outp);
}